// Round 13
// baseline (127.718 us; speedup 1.0000x reference)
//
#include <hip/hip_runtime.h>

// CRITICAL: hipcc defaults to -ffp-contract=fast-honor-pragmas, and HIP's
// __fmul_rn/__fadd_rn are PLAIN OPERATORS (not contraction barriers like
// CUDA). This pragma guarantees mul/add are not fused into v_fmac, so our
// rounding matches numpy's exactly. (R4 proved this: absmax == 0.0.)
#pragma clang fp contract(off)

static __device__ __forceinline__ float min3f(float a, float b, float c) {
    float d;
    asm("v_min3_f32 %0, %1, %2, %3" : "=v"(d) : "v"(a), "v"(b), "v"(c));
    return d;
}

// Problem constants (from reference): B=4, N=16384, M=4096, D=64
#define MM 4096
#define DD 64
#define BN 65536                  // B*N points
#define FEATS_OFF 0               // feats: BN*DD floats
#define IDS_OFF (BN * DD)         // ids:   BN floats (ints stored as float)
#define PC_OFF (IDS_OFF + BN)     // pc:    BN*3 floats passthrough

#define BLK 512                   // threads per block (8 waves)
#define CC 32                     // lanes per point
#define PP 8                      // points per thread (register tile)
#define PPB 128                   // points per block (BLK*PP/CC)
#define NPG (BN / PPB)            // 512 point-groups
#define HPAIR 1024                // key pairs per half (2048 keys)
#define KIT (HPAIR / CC)          // 32 main-loop iterations

// NUMERICS (bit-exact vs numpy fp32 replay — verified R4-R12, absmax==0):
//  - keys stored NEGATED+DOUBLED: rn commutes with sign/2^k scaling, so
//    d2 = (psq + cross') + ksq == (psq - 2*cross) + ksq == reference bits.
//  - all plain rn (contract off); k_sq/p_sq ascending plain.
//  - argmin: min3 strict-drop keeps first iter; even key preferred on
//    within-pair tie; lexicographic (d2,id) merges (butterfly + cross-half)
//    => numpy first-index tie-break.
//
// STRUCTURE (R13): R12 proved occupancy is NOT the limiter (2x residency,
// same 60 us) — the fp32 pipe is. Cycle model fits R9/R12 walls iff
// v_pk_*_f32 is HALF-RATE per fp32 op (~8 cyc pipe occupancy/wave-instr;
// fp32 peak 157 TF == scalar rate). So: SCALAR plain mul/add chain
// (14 instr/pair, full rate) + min3/deferred-k bookkeeping (3 instr/pair).
// Model: 8 waves/SIMD x 32 iters x 8 pts x 34 cyc ~= 29 us scan.
__global__ __launch_bounds__(BLK, 4)
void quant_scan_kernel(const float* __restrict__ pc,
                       const float* __restrict__ keys,
                       float* __restrict__ bdws,
                       int* __restrict__ bmws)
{
#pragma clang fp contract(off)
    __shared__ float4 skA[HPAIR];  // (-2kx_e,-2kx_o,-2ky_e,-2ky_o) 16 KiB
    __shared__ float4 skB[HPAIR];  // (-2kz_e,-2kz_o, ksq_e, ksq_o) 16 KiB

    const int tid = threadIdx.x;
    const int pg   = blockIdx.x & (NPG - 1);   // point-group 0..511
    const int half = blockIdx.x >> 9;          // key-half 0 or 1

    // Stage this half's key pairs (2/thread). Global pair jg = half*1024+jl;
    // pair = keys 2jg (f0.x,f0.y,f1.x) and 2jg+1 (f1.y,f2.x,f2.y).
    #pragma unroll
    for (int i = 0; i < HPAIR / BLK; ++i) {
        const int jl = tid + i * BLK;
        const int jg = (half << 10) + jl;
        const float2 f0 = ((const float2*)keys)[3 * jg + 0];
        const float2 f1 = ((const float2*)keys)[3 * jg + 1];
        const float2 f2 = ((const float2*)keys)[3 * jg + 2];
        const float ksq0 = ((f0.x * f0.x) + (f0.y * f0.y)) + (f1.x * f1.x);
        const float ksq1 = ((f1.y * f1.y) + (f2.x * f2.x)) + (f2.y * f2.y);
        skA[jl] = make_float4(-2.0f * f0.x, -2.0f * f1.y,
                              -2.0f * f0.y, -2.0f * f2.x);
        skB[jl] = make_float4(-2.0f * f1.x, -2.0f * f2.y, ksq0, ksq1);
    }

    const int c = tid & (CC - 1);
    const int g = tid >> 5;                    // point-group-local 0..15
    const int p0 = pg * PPB + g * PP;          // my first point

    // Load my 8 points (24 floats = 6 float4, aligned: 3*p0 % 4 == 0).
    float arr[24];
    {
        const float4* pcv = (const float4*)(pc + 3 * p0);
        #pragma unroll
        for (int i = 0; i < 6; ++i) ((float4*)arr)[i] = pcv[i];
    }
    float px[PP], py[PP], pz[PP], psq[PP], bd[PP];
    int bk[PP];
    #pragma unroll
    for (int i = 0; i < PP; ++i) {
        px[i] = arr[3 * i + 0];
        py[i] = arr[3 * i + 1];
        pz[i] = arr[3 * i + 2];
        psq[i] = ((px[i] * px[i]) + (py[i] * py[i])) + (pz[i] * pz[i]);
        bd[i] = 3.402823466e38f;
        bk[i] = 0;
    }

    __syncthreads();

    // Main loop over this half: lane c, iter k -> local pair jl = 32k + c.
    // SCALAR exact chain, both keys of the pair, then min3 bookkeeping.
    #pragma unroll 2
    for (int k = 0; k < KIT; ++k) {
        const int j = (k << 5) + c;
        const float4 A  = skA[j];
        const float4 Bv = skB[j];
        #pragma unroll
        for (int i = 0; i < PP; ++i) {
            const float ca = ((px[i] * A.x) + (py[i] * A.z)) + (pz[i] * Bv.x);
            const float da = (psq[i] + ca) + Bv.z;       // even key
            const float cb = ((px[i] * A.y) + (py[i] * A.w)) + (pz[i] * Bv.y);
            const float db = (psq[i] + cb) + Bv.w;       // odd key
            const float nb = min3f(bd[i], da, db);
            const bool ch = nb < bd[i];  // strict drop => first-index kept
            bd[i] = nb;
            bk[i] = ch ? k : bk[i];
        }
    }

    // Recover winning key within pair bk[i] (same scalar chain => same
    // bits), then butterfly-merge the 32 lanes; lane 0 writes the champion.
    #pragma unroll
    for (int i = 0; i < PP; ++i) {
        const int jl = (bk[i] << 5) + c;
        const float4 Ar = skA[jl];
        const float4 Br = skB[jl];
        const float ca = ((px[i] * Ar.x) + (py[i] * Ar.z)) + (pz[i] * Br.x);
        const float da = (psq[i] + ca) + Br.z;
        const int m0 = (((half << 10) + jl) << 1);
        float d = bd[i];
        int   m = (da == bd[i]) ? m0 : (m0 + 1);  // even preferred on tie
        #pragma unroll
        for (int off = 1; off < CC; off <<= 1) {
            const float od = __shfl_xor(d, off);
            const int   om = __shfl_xor(m, off);
            if (od < d || (od == d && om < m)) { d = od; m = om; }
        }
        if (c == 0) {
            bdws[half * BN + p0 + i] = d;
            bmws[half * BN + p0 + i] = m;
        }
    }
}

// Kernel 2: merge the two halves (exact fp32 lexicographic), gather value
// rows, write feats + ids, and copy the pc passthrough.
__global__ __launch_bounds__(256)
void merge_gather_kernel(const float* __restrict__ pc,
                         const float* __restrict__ values,
                         const float* __restrict__ bdws,
                         const int* __restrict__ bmws,
                         float* __restrict__ out)
{
    const int tid = threadIdx.x;
    const int c = tid & 15;                       // lane within point
    const int p = blockIdx.x * 16 + (tid >> 4);   // point id

    const float d0 = bdws[p];
    const float d1 = bdws[BN + p];
    const int   m0 = bmws[p];
    const int   m1 = bmws[BN + p];
    // Half-0 ids are all smaller than half-1 ids, so on exact tie keep m0.
    const int m = (d1 < d0) ? m1 : m0;

    const float4 v = ((const float4*)(values + (size_t)m * DD))[c];
    ((float4*)(out + FEATS_OFF + (size_t)p * DD))[c] = v;
    if (c == 0) out[IDS_OFF + p] = (float)m;

    // pc passthrough: 196608 floats = 49152 float4 spread over the grid.
    const int gt = blockIdx.x * 256 + tid;
    if (gt < BN * 3 / 4) {
        ((float4*)(out + PC_OFF))[gt] = ((const float4*)pc)[gt];
    }
}

extern "C" void kernel_launch(void* const* d_in, const int* in_sizes, int n_in,
                              void* d_out, int out_size, void* d_ws, size_t ws_size,
                              hipStream_t stream) {
    const float* pc     = (const float*)d_in[0];
    const float* keys   = (const float*)d_in[1];
    const float* values = (const float*)d_in[2];
    float* out = (float*)d_out;

    float* bdws = (float*)d_ws;                  // 2*BN floats
    int*   bmws = (int*)d_ws + 2 * BN;           // 2*BN ints   (1 MB total)

    quant_scan_kernel<<<dim3(2 * NPG), dim3(BLK), 0, stream>>>(pc, keys, bdws, bmws);
    merge_gather_kernel<<<dim3(BN / 16), dim3(256), 0, stream>>>(pc, values, bdws, bmws, out);
}

// Round 14
// 125.580 us; speedup vs baseline: 1.0170x; 1.0170x over previous
//
#include <hip/hip_runtime.h>

// CRITICAL: hipcc defaults to -ffp-contract=fast-honor-pragmas, and HIP's
// __fmul_rn/__fadd_rn are PLAIN OPERATORS (not contraction barriers like
// CUDA). This pragma guarantees mul/add are not fused into v_fmac, so our
// rounding matches numpy's exactly. (R4 proved this: absmax == 0.0.)
#pragma clang fp contract(off)

static __device__ __forceinline__ float min3f(float a, float b, float c) {
    float d;
    asm("v_min3_f32 %0, %1, %2, %3" : "=v"(d) : "v"(a), "v"(b), "v"(c));
    return d;
}

// Problem constants (from reference): B=4, N=16384, M=4096, D=64
#define MM 4096
#define DD 64
#define BN 65536                  // B*N points
#define FEATS_OFF 0               // feats: BN*DD floats
#define IDS_OFF (BN * DD)         // ids:   BN floats (ints stored as float)
#define PC_OFF (IDS_OFF + BN)     // pc:    BN*3 floats passthrough

#define BLK 512                   // threads per block (8 waves)
#define CC 16                     // lanes per point
#define PP 4                      // points per thread (register tile)
#define PPB 128                   // points per block (BLK*PP/CC)
#define NPG (BN / PPB)            // 512 point-groups
#define HPAIR 1024                // key pairs per half (2048 keys)
#define KIT (HPAIR / CC)          // 64 main-loop iterations
#define PSLOT(j) ((j) + ((j) >> 3))   // padded LDS slot (1 float4 per 8)
#define PADN (HPAIR + HPAIR / 8)      // 1152 slots per array

// NUMERICS (bit-exact vs numpy fp32 replay — verified R4-R13, absmax==0):
//  - keys stored NEGATED+DOUBLED: rn commutes with sign/2^k scaling, so
//    d2 = (psq + cross') + ksq == (psq - 2*cross) + ksq == reference bits.
//  - all plain rn (contract off); k_sq/p_sq ascending plain.
//  - argmin: min3 strict-drop keeps first iter; even key preferred on
//    within-pair tie; lexicographic (d2,id) merges (butterfly + cross-half)
//    => numpy first-index tie-break.
//
// STRUCTURE (R14): cycle model refit across R6/R8/R12/R13: scalar
// v_mul/v_add = 2 cyc/instr (full rate); v_pk_*_f32 ~ 8 cyc (quarter rate,
// no fp32 throughput gain) — R12's pk loop was off-floor; R13's scalar try
// collapsed the allocator (PP=8 needs ~66 regs -> VGPR 36 + spill movs).
// Fix: scalar chain with PP=4/CC=16 (~45 live regs, safe), LDS pad
// j+(j>>3) so reads are slot 18k+c0 (2-way banks = free, 1 v_add/iter).
// Busy floor: 64 it x 4 pts x 34 cyc x 8 waves/SIMD ~= 30 us.
__global__ __launch_bounds__(BLK, 4)
void quant_scan_kernel(const float* __restrict__ pc,
                       const float* __restrict__ keys,
                       float* __restrict__ bdws,
                       int* __restrict__ bmws)
{
#pragma clang fp contract(off)
    __shared__ float4 skA[PADN];  // (-2kx_e,-2kx_o,-2ky_e,-2ky_o) 18 KiB
    __shared__ float4 skB[PADN];  // (-2kz_e,-2kz_o, ksq_e, ksq_o) 18 KiB

    const int tid = threadIdx.x;
    const int pg   = blockIdx.x & (NPG - 1);   // point-group 0..511
    const int half = blockIdx.x >> 9;          // key-half 0 or 1

    // Stage this half's key pairs (2/thread) into padded slots.
    // Pair jl = keys 2jg (f0.x,f0.y,f1.x) and 2jg+1 (f1.y,f2.x,f2.y).
    #pragma unroll
    for (int i = 0; i < HPAIR / BLK; ++i) {
        const int jl = tid + i * BLK;
        const int jg = (half << 10) + jl;
        const float2 f0 = ((const float2*)keys)[3 * jg + 0];
        const float2 f1 = ((const float2*)keys)[3 * jg + 1];
        const float2 f2 = ((const float2*)keys)[3 * jg + 2];
        const float ksq0 = ((f0.x * f0.x) + (f0.y * f0.y)) + (f1.x * f1.x);
        const float ksq1 = ((f1.y * f1.y) + (f2.x * f2.x)) + (f2.y * f2.y);
        skA[PSLOT(jl)] = make_float4(-2.0f * f0.x, -2.0f * f1.y,
                                     -2.0f * f0.y, -2.0f * f2.x);
        skB[PSLOT(jl)] = make_float4(-2.0f * f1.x, -2.0f * f2.y, ksq0, ksq1);
    }

    const int c = tid & (CC - 1);
    const int g = tid >> 4;                    // point-group-local 0..31
    const int p0 = pg * PPB + g * PP;          // my first point

    // Load my 4 points (12 floats = 3 float4, aligned: 3*p0 % 4 == 0).
    float arr[12];
    {
        const float4* pcv = (const float4*)(pc + 3 * p0);
        #pragma unroll
        for (int i = 0; i < 3; ++i) ((float4*)arr)[i] = pcv[i];
    }
    float px[PP], py[PP], pz[PP], psq[PP], bd[PP];
    int bk[PP];
    #pragma unroll
    for (int i = 0; i < PP; ++i) {
        px[i] = arr[3 * i + 0];
        py[i] = arr[3 * i + 1];
        pz[i] = arr[3 * i + 2];
        psq[i] = ((px[i] * px[i]) + (py[i] * py[i])) + (pz[i] * pz[i]);
        bd[i] = 3.402823466e38f;
        bk[i] = 0;
    }

    __syncthreads();

    // Main loop: lane c, iter k -> pair jl = 16k + c at padded slot
    // 18k + c0 (linear stride 18; 2-way banks free; quad-broadcast).
    const int c0 = PSLOT(c);
    int sl = c0;
    #pragma unroll 2
    for (int k = 0; k < KIT; ++k) {
        const float4 A  = skA[sl];
        const float4 Bv = skB[sl];
        sl += 18;
        #pragma unroll
        for (int i = 0; i < PP; ++i) {
            const float ca = ((px[i] * A.x) + (py[i] * A.z)) + (pz[i] * Bv.x);
            const float da = (psq[i] + ca) + Bv.z;       // even key
            const float cb = ((px[i] * A.y) + (py[i] * A.w)) + (pz[i] * Bv.y);
            const float db = (psq[i] + cb) + Bv.w;       // odd key
            const float nb = min3f(bd[i], da, db);
            const bool ch = nb < bd[i];  // strict drop => first-index kept
            bd[i] = nb;
            bk[i] = ch ? k : bk[i];
        }
    }

    // Recover winning key within pair bk[i] (same scalar chain => same
    // bits), then butterfly-merge the 16 lanes; lane 0 writes the champion.
    #pragma unroll
    for (int i = 0; i < PP; ++i) {
        const int rs = bk[i] * 18 + c0;            // padded slot of my pair
        const float4 Ar = skA[rs];
        const float4 Br = skB[rs];
        const float ca = ((px[i] * Ar.x) + (py[i] * Ar.z)) + (pz[i] * Br.x);
        const float da = (psq[i] + ca) + Br.z;
        const int m0 = (((half << 10) + (bk[i] << 4) + c) << 1);
        float d = bd[i];
        int   m = (da == bd[i]) ? m0 : (m0 + 1);  // even preferred on tie
        #pragma unroll
        for (int off = 1; off < CC; off <<= 1) {
            const float od = __shfl_xor(d, off);
            const int   om = __shfl_xor(m, off);
            if (od < d || (od == d && om < m)) { d = od; m = om; }
        }
        if (c == 0) {
            bdws[half * BN + p0 + i] = d;
            bmws[half * BN + p0 + i] = m;
        }
    }
}

// Kernel 2: merge the two halves (exact fp32 lexicographic), gather value
// rows, write feats + ids, and copy the pc passthrough.
__global__ __launch_bounds__(256)
void merge_gather_kernel(const float* __restrict__ pc,
                         const float* __restrict__ values,
                         const float* __restrict__ bdws,
                         const int* __restrict__ bmws,
                         float* __restrict__ out)
{
    const int tid = threadIdx.x;
    const int c = tid & 15;                       // lane within point
    const int p = blockIdx.x * 16 + (tid >> 4);   // point id

    const float d0 = bdws[p];
    const float d1 = bdws[BN + p];
    const int   m0 = bmws[p];
    const int   m1 = bmws[BN + p];
    // Half-0 ids are all smaller than half-1 ids, so on exact tie keep m0.
    const int m = (d1 < d0) ? m1 : m0;

    const float4 v = ((const float4*)(values + (size_t)m * DD))[c];
    ((float4*)(out + FEATS_OFF + (size_t)p * DD))[c] = v;
    if (c == 0) out[IDS_OFF + p] = (float)m;

    // pc passthrough: 196608 floats = 49152 float4 spread over the grid.
    const int gt = blockIdx.x * 256 + tid;
    if (gt < BN * 3 / 4) {
        ((float4*)(out + PC_OFF))[gt] = ((const float4*)pc)[gt];
    }
}

extern "C" void kernel_launch(void* const* d_in, const int* in_sizes, int n_in,
                              void* d_out, int out_size, void* d_ws, size_t ws_size,
                              hipStream_t stream) {
    const float* pc     = (const float*)d_in[0];
    const float* keys   = (const float*)d_in[1];
    const float* values = (const float*)d_in[2];
    float* out = (float*)d_out;

    float* bdws = (float*)d_ws;                  // 2*BN floats
    int*   bmws = (int*)d_ws + 2 * BN;           // 2*BN ints   (1 MB total)

    quant_scan_kernel<<<dim3(2 * NPG), dim3(BLK), 0, stream>>>(pc, keys, bdws, bmws);
    merge_gather_kernel<<<dim3(BN / 16), dim3(256), 0, stream>>>(pc, values, bdws, bmws, out);
}